// Round 1
// baseline (1160.055 us; speedup 1.0000x reference)
//
#include <hip/hip_runtime.h>
#include <hip/hip_bf16.h>
#include <stdint.h>

#define D_MODEL 1024
#define D_FF    4096
#define NE      8
#define NTOK    8192
#define OUT_MAIN (NTOK * D_MODEL)

typedef float f32x4 __attribute__((ext_vector_type(4)));
typedef short s16x8 __attribute__((ext_vector_type(8)));

struct __align__(8) bh4 { __hip_bfloat16 x, y, z, w; };

// ---- workspace layout (bytes). total required: 285,474,816 (~272.3 MB) ----
// [0,4096)        ctrl: int cnt[8]; int cursor[8]; int off[8]; float probsum[8]
// [4096,36864)    e12  : int[8192]   (e1 | e2<<8 per token)
// [36864,102400)  pfr  : float2[8192] renormalized top-2 probs
// [102400,167936) atok : int[16384]  slot -> token
// [167936,233472) ap   : float[16384] slot -> prob
// [262144,..)     xb   : bf16[8192*1024]
// then w1t bf16[8][4096][1024] (transposed), w2t bf16[8][1024][4096], h bf16[16384*4096]
static const size_t OFF_E12  = 4096;
static const size_t OFF_PFR  = 36864;
static const size_t OFF_ATOK = 102400;
static const size_t OFF_AP   = 167936;
static const size_t OFF_XB   = 262144;
static const size_t OFF_W1T  = OFF_XB  + (size_t)NTOK * D_MODEL * 2;       // 17039360
static const size_t OFF_W2T  = OFF_W1T + (size_t)NE * D_MODEL * D_FF * 2;  // 84148224
static const size_t OFF_H    = OFF_W2T + (size_t)NE * D_MODEL * D_FF * 2;  // 151257088

__device__ inline void gll16(const void* g, void* lds) {
  __builtin_amdgcn_global_load_lds((__attribute__((address_space(1))) void*)g,
                                   (__attribute__((address_space(3))) void*)lds,
                                   16, 0, 0);
}

// ---------------- weight convert + transpose: src [E][K][N] f32 -> dst [E][N][K] bf16 ----------------
__global__ __launch_bounds__(256) void cvt_transpose_kernel(
    const float* __restrict__ src, __hip_bfloat16* __restrict__ dst, int K, int N)
{
  __shared__ __hip_bfloat16 tile[64][68];
  const int e = blockIdx.z;
  const float* s = src + (size_t)e * K * N;
  __hip_bfloat16* d = dst + (size_t)e * K * N;
  const int n0 = blockIdx.x * 64, k0 = blockIdx.y * 64;
  const int t = threadIdx.x;
#pragma unroll
  for (int i = 0; i < 4; ++i) {
    int q = i * 256 + t;
    int r = q >> 4, c4 = (q & 15) * 4;
    float4 v = *(const float4*)(s + (size_t)(k0 + r) * N + n0 + c4);
    tile[r][c4 + 0] = __float2bfloat16(v.x);
    tile[r][c4 + 1] = __float2bfloat16(v.y);
    tile[r][c4 + 2] = __float2bfloat16(v.z);
    tile[r][c4 + 3] = __float2bfloat16(v.w);
  }
  __syncthreads();
  const int n = t >> 2, c = (t & 3) * 16;
  __align__(16) __hip_bfloat16 tmp[16];
#pragma unroll
  for (int j = 0; j < 16; ++j) tmp[j] = tile[c + j][n];
  uint4* tv = (uint4*)tmp;
  __hip_bfloat16* dp = d + (size_t)(n0 + n) * K + k0 + c;
  ((uint4*)dp)[0] = tv[0];
  ((uint4*)dp)[1] = tv[1];
}

// ---------------- router: logits, softmax, top-2, stats; also emits x as bf16 ----------------
__global__ __launch_bounds__(256) void router_kernel(
    const float* __restrict__ x, const float* __restrict__ gw, const float* __restrict__ gb,
    __hip_bfloat16* __restrict__ xb, int* __restrict__ e12, float2* __restrict__ pfr,
    int* __restrict__ cnt, float* __restrict__ probsum)
{
  const int l = threadIdx.x & 63;
  const int t = blockIdx.x * 4 + (threadIdx.x >> 6);
  const float4* xr = (const float4*)(x + (size_t)t * D_MODEL);
  bh4* xbr = (bh4*)(xb + (size_t)t * D_MODEL);
  float a[8] = {0, 0, 0, 0, 0, 0, 0, 0};
#pragma unroll
  for (int c = 0; c < 4; ++c) {
    int idx = c * 64 + l;
    float4 v = xr[idx];
    bh4 hb;
    hb.x = __float2bfloat16(v.x); hb.y = __float2bfloat16(v.y);
    hb.z = __float2bfloat16(v.z); hb.w = __float2bfloat16(v.w);
    xbr[idx] = hb;
    const float* g = gw + (size_t)idx * 32;  // 4 rows x 8 experts
#pragma unroll
    for (int j = 0; j < 4; ++j) {
      float xv = (&v.x)[j];
#pragma unroll
      for (int e = 0; e < 8; ++e) a[e] = fmaf(xv, g[j * 8 + e], a[e]);
    }
  }
#pragma unroll
  for (int e = 0; e < 8; ++e) {
    float s = a[e];
#pragma unroll
    for (int off = 32; off > 0; off >>= 1) s += __shfl_xor(s, off, 64);
    a[e] = s + gb[e];
  }
  float m = a[0];
#pragma unroll
  for (int e = 1; e < 8; ++e) m = fmaxf(m, a[e]);
  float p[8], s = 0.f;
#pragma unroll
  for (int e = 0; e < 8; ++e) { p[e] = expf(a[e] - m); s += p[e]; }
  float inv = 1.0f / s;
#pragma unroll
  for (int e = 0; e < 8; ++e) p[e] *= inv;
  int e1 = 0; float p1 = p[0];
#pragma unroll
  for (int e = 1; e < 8; ++e) if (p[e] > p1) { p1 = p[e]; e1 = e; }
  int e2 = (e1 == 0) ? 1 : 0; float p2 = p[e2];
#pragma unroll
  for (int e = 0; e < 8; ++e) if (e != e1 && p[e] > p2) { p2 = p[e]; e2 = e; }

  if (l < 8) unsafeAtomicAdd(probsum + l, p[l]);
  if (l == 0) {
    float rs = 1.0f / (p1 + p2);
    e12[t] = e1 | (e2 << 8);
    pfr[t] = make_float2(p1 * rs, p2 * rs);
    atomicAdd(cnt + e1, 1);
    atomicAdd(cnt + e2, 1);
  }
}

// ---------------- finalize: offsets + usage + load-balance loss ----------------
__global__ void finalize_kernel(int* __restrict__ ctrl, float* __restrict__ probsum,
                                float* __restrict__ out_tail)
{
  if (threadIdx.x != 0) return;
  int off = 0;
  float avg[8]; float mean = 0.f;
#pragma unroll
  for (int e = 0; e < 8; ++e) {
    int c = ctrl[e];
    ctrl[8 + e]  = off;  // cursor (mutated by scatter)
    ctrl[16 + e] = off;  // stable offset for GEMMs
    off += c;
    out_tail[e] = (float)c * (1.0f / 16384.0f);
    avg[e] = probsum[e] * (1.0f / 8192.0f);
    mean += avg[e];
  }
  mean *= 0.125f;
  float v = 0.f;
#pragma unroll
  for (int e = 0; e < 8; ++e) { float d = avg[e] - mean; v += d * d; }
  out_tail[8] = v * (1.0f / 7.0f);  // ddof=1
}

// ---------------- scatter: build per-expert (token, prob) slot lists ----------------
__global__ __launch_bounds__(256) void scatter_kernel(
    const int* __restrict__ e12, const float2* __restrict__ pfr,
    int* __restrict__ cursor, int* __restrict__ atok, float* __restrict__ ap)
{
  int t = blockIdx.x * 256 + threadIdx.x;
  int ee = e12[t];
  float2 p = pfr[t];
  int pos0 = atomicAdd(cursor + (ee & 0xff), 1);
  atok[pos0] = t; ap[pos0] = p.x;
  int pos1 = atomicAdd(cursor + (ee >> 8), 1);
  atok[pos1] = t; ap[pos1] = p.y;
}

// ---------------- grouped GEMM, 128x128 tile, BK=64, 16x16x32 bf16 MFMA ----------------
// G1: h[slot][4096] = relu( xb[tok[slot]][1024] @ w1t^T + b1 )   (w1t is [N][K])
// G2: out[tok][1024] += ap[slot] * ( h[slot][4096] @ w2t^T + b2 )
template <bool G1>
__global__ __launch_bounds__(256) void moe_gemm_kernel(
    const __hip_bfloat16* __restrict__ A, const __hip_bfloat16* __restrict__ Bw,
    const float* __restrict__ bias, __hip_bfloat16* __restrict__ Hout,
    float* __restrict__ Oout, const int* __restrict__ ctrl,
    const int* __restrict__ atok, const float* __restrict__ ap)
{
  constexpr int KD = G1 ? D_MODEL : D_FF;
  constexpr int ND = G1 ? D_FF : D_MODEL;
  constexpr int KITERS = KD / 64;
  const int e = blockIdx.z;
  const int cte = ctrl[e];
  const int mt = blockIdx.y;
  if (mt * 128 >= cte) return;  // early-exit: fixed worst-case grid, data-dependent live set
  const int n0 = blockIdx.x * 128;
  const int slot0 = ctrl[16 + e] + mt * 128;
  int cntLoc = cte - mt * 128; if (cntLoc > 128) cntLoc = 128;

  __shared__ ushort As[128 * 64];
  __shared__ ushort Bs[128 * 64];

  const int t = threadIdx.x, l = t & 63, w = t >> 6;

  // staging pointers: chunk q = i*256+t covers (row = q>>3, lds-chunk = q&7); global chunk is
  // XOR-swizzled (cg = cl ^ (row&7)) so fragment ds_read_b128s are conflict-free.
  const ushort* ag[4];
  const ushort* bg[4];
#pragma unroll
  for (int i = 0; i < 4; ++i) {
    int q = i * 256 + t;
    int row = q >> 3, cl = q & 7, cg = cl ^ (row & 7);
    int rr = row < cntLoc ? row : 0;  // clamp padded rows to a valid slot
    size_t arow;
    if constexpr (G1) arow = (size_t)atok[slot0 + rr] * D_MODEL;
    else              arow = (size_t)(slot0 + rr) * D_FF;
    ag[i] = (const ushort*)A + arow + cg * 8;
    bg[i] = (const ushort*)Bw + (size_t)e * ND * KD + (size_t)(n0 + row) * KD + cg * 8;
  }

  f32x4 acc[4][4] = {};
  const int wm = w & 1, wn = w >> 1;
  const int ml = l & 15, kg = l >> 4;

  for (int kt = 0; kt < KITERS; ++kt) {
#pragma unroll
    for (int i = 0; i < 4; ++i) {
      gll16(ag[i], &As[(i * 256 + w * 64) * 8]);
      ag[i] += 64;
    }
#pragma unroll
    for (int i = 0; i < 4; ++i) {
      gll16(bg[i], &Bs[(i * 256 + w * 64) * 8]);
      bg[i] += 64;
    }
    __syncthreads();  // drains vmcnt -> tiles resident
#pragma unroll
    for (int ks = 0; ks < 2; ++ks) {
      s16x8 af[4], bf[4];
#pragma unroll
      for (int mi = 0; mi < 4; ++mi) {
        int row = wm * 64 + mi * 16 + ml;
        int c = ks * 4 + kg;
        af[mi] = *(const s16x8*)&As[row * 64 + ((c ^ (row & 7)) * 8)];
      }
#pragma unroll
      for (int ni = 0; ni < 4; ++ni) {
        int row = wn * 64 + ni * 16 + ml;
        int c = ks * 4 + kg;
        bf[ni] = *(const s16x8*)&Bs[row * 64 + ((c ^ (row & 7)) * 8)];
      }
#pragma unroll
      for (int mi = 0; mi < 4; ++mi)
#pragma unroll
        for (int ni = 0; ni < 4; ++ni)
          acc[mi][ni] = __builtin_amdgcn_mfma_f32_16x16x32_bf16(af[mi], bf[ni], acc[mi][ni], 0, 0, 0);
    }
    __syncthreads();
  }

  // C/D layout (m89/m91-verified): col = lane&15, row = (lane>>4)*4 + reg
  const int lr = kg * 4, lc = ml;
  if constexpr (G1) {
#pragma unroll
    for (int ni = 0; ni < 4; ++ni) {
      int col = n0 + wn * 64 + ni * 16 + lc;
      float bv = bias[(size_t)e * ND + col];
#pragma unroll
      for (int mi = 0; mi < 4; ++mi) {
#pragma unroll
        for (int r = 0; r < 4; ++r) {
          int rl = wm * 64 + mi * 16 + lr + r;
          if (rl < cntLoc) {
            float vv = fmaxf(acc[mi][ni][r] + bv, 0.0f);
            Hout[(size_t)(slot0 + rl) * D_FF + col] = __float2bfloat16(vv);
          }
        }
      }
    }
  } else {
    float bv[4];
#pragma unroll
    for (int ni = 0; ni < 4; ++ni)
      bv[ni] = bias[(size_t)e * ND + n0 + wn * 64 + ni * 16 + lc];
#pragma unroll
    for (int mi = 0; mi < 4; ++mi) {
#pragma unroll
      for (int r = 0; r < 4; ++r) {
        int rl = wm * 64 + mi * 16 + lr + r;
        if (rl < cntLoc) {
          int slot = slot0 + rl;
          float p = ap[slot];
          float* orow = Oout + (size_t)atok[slot] * D_MODEL + n0;
#pragma unroll
          for (int ni = 0; ni < 4; ++ni) {
            int colL = wn * 64 + ni * 16 + lc;
            unsafeAtomicAdd(orow + colL, p * (acc[mi][ni][r] + bv[ni]));
          }
        }
      }
    }
  }
}

extern "C" void kernel_launch(void* const* d_in, const int* in_sizes, int n_in,
                              void* d_out, int out_size, void* d_ws, size_t ws_size,
                              hipStream_t stream)
{
  const float* x  = (const float*)d_in[0];
  const float* gw = (const float*)d_in[1];
  const float* gb = (const float*)d_in[2];
  const float* w1 = (const float*)d_in[3];
  const float* b1 = (const float*)d_in[4];
  const float* w2 = (const float*)d_in[5];
  const float* b2 = (const float*)d_in[6];
  float* out = (float*)d_out;
  char* ws = (char*)d_ws;

  int*    ctrl    = (int*)ws;            // cnt[8], cursor[8], off[8]
  float*  probsum = (float*)ws + 24;
  int*    e12  = (int*)(ws + OFF_E12);
  float2* pfr  = (float2*)(ws + OFF_PFR);
  int*    atok = (int*)(ws + OFF_ATOK);
  float*  ap   = (float*)(ws + OFF_AP);
  __hip_bfloat16* xb   = (__hip_bfloat16*)(ws + OFF_XB);
  __hip_bfloat16* w1t  = (__hip_bfloat16*)(ws + OFF_W1T);
  __hip_bfloat16* w2t  = (__hip_bfloat16*)(ws + OFF_W2T);
  __hip_bfloat16* hbuf = (__hip_bfloat16*)(ws + OFF_H);

  hipMemsetAsync(d_out, 0, (size_t)out_size * sizeof(float), stream);
  hipMemsetAsync(d_ws, 0, 4096, stream);

  cvt_transpose_kernel<<<dim3(D_FF / 64, D_MODEL / 64, NE), 256, 0, stream>>>(w1, w1t, D_MODEL, D_FF);
  cvt_transpose_kernel<<<dim3(D_MODEL / 64, D_FF / 64, NE), 256, 0, stream>>>(w2, w2t, D_FF, D_MODEL);
  router_kernel<<<NTOK / 4, 256, 0, stream>>>(x, gw, gb, xb, e12, pfr, ctrl, probsum);
  finalize_kernel<<<1, 64, 0, stream>>>(ctrl, probsum, out + OUT_MAIN);
  scatter_kernel<<<NTOK / 256, 256, 0, stream>>>(e12, pfr, ctrl + 8, atok, ap);
  moe_gemm_kernel<true ><<<dim3(D_FF / 128, 64, NE), 256, 0, stream>>>(xb, w1t, b1, hbuf, nullptr, ctrl, atok, ap);
  moe_gemm_kernel<false><<<dim3(D_MODEL / 128, 64, NE), 256, 0, stream>>>(hbuf, w2t, b2, nullptr, out, ctrl, atok, ap);
}

// Round 3
// 932.140 us; speedup vs baseline: 1.2445x; 1.2445x over previous
//
#include <hip/hip_runtime.h>
#include <hip/hip_bf16.h>
#include <stdint.h>

#define D_MODEL 1024
#define D_FF    4096
#define NE      8
#define NTOK    8192
#define OUT_MAIN (NTOK * D_MODEL)

typedef float f32x4 __attribute__((ext_vector_type(4)));
typedef short s16x8 __attribute__((ext_vector_type(8)));

struct __align__(8) bh4 { __hip_bfloat16 x, y, z, w; };

// ---- workspace layout (bytes). total: 285,474,816 (~272.3 MB) ----
// [0,1024)        ctrl: int cnt[8] @0; int expoff[8] @ints 16..23  (finalize is sole writer)
// [1024,2048)     bases: int[32][8] per-(block, expert) global placement base
// [3072,4096)     sblkcnt: int[32][8]
// [4096,36864)    e12 : int[8192] (e1 | e2<<8)
// [36864,102400)  pfr : float2[8192] renormalized top-2 probs
// [102400,167936) atok: int[16384] slot -> token
// [167936,233472) ap  : float[16384] slot -> prob
// [262144,..)     xb bf16; w1t bf16 [E][4096][1024]; w2t bf16 [E][1024][4096]; h bf16[16384*4096]
// blkps float[2048][8] ALIASES the start of hbuf (dead before GEMM1 writes hbuf).
static const size_t OFF_E12   = 4096;
static const size_t OFF_PFR   = 36864;
static const size_t OFF_ATOK  = 102400;
static const size_t OFF_AP    = 167936;
static const size_t OFF_XB    = 262144;
static const size_t OFF_W1T   = OFF_XB  + (size_t)NTOK * D_MODEL * 2;
static const size_t OFF_W2T   = OFF_W1T + (size_t)NE * D_MODEL * D_FF * 2;
static const size_t OFF_H     = OFF_W2T + (size_t)NE * D_MODEL * D_FF * 2;

__device__ inline void gll16(const void* g, void* lds) {
  __builtin_amdgcn_global_load_lds((__attribute__((address_space(1))) void*)g,
                                   (__attribute__((address_space(3))) void*)lds,
                                   16, 0, 0);
}

// ---------------- weight convert + transpose: src [E][K][N] f32 -> dst [E][N][K] bf16 ----------------
__global__ __launch_bounds__(256) void cvt_transpose_kernel(
    const float* __restrict__ src, __hip_bfloat16* __restrict__ dst, int K, int N)
{
  __shared__ __hip_bfloat16 tile[64][68];
  const int e = blockIdx.z;
  const float* s = src + (size_t)e * K * N;
  __hip_bfloat16* d = dst + (size_t)e * K * N;
  const int n0 = blockIdx.x * 64, k0 = blockIdx.y * 64;
  const int t = threadIdx.x;
#pragma unroll
  for (int i = 0; i < 4; ++i) {
    int q = i * 256 + t;
    int r = q >> 4, c4 = (q & 15) * 4;
    float4 v = *(const float4*)(s + (size_t)(k0 + r) * N + n0 + c4);
    tile[r][c4 + 0] = __float2bfloat16(v.x);
    tile[r][c4 + 1] = __float2bfloat16(v.y);
    tile[r][c4 + 2] = __float2bfloat16(v.z);
    tile[r][c4 + 3] = __float2bfloat16(v.w);
  }
  __syncthreads();
  const int n = t >> 2, c = (t & 3) * 16;
  __align__(16) __hip_bfloat16 tmp[16];
#pragma unroll
  for (int j = 0; j < 16; ++j) tmp[j] = tile[c + j][n];
  uint4* tv = (uint4*)tmp;
  __hip_bfloat16* dp = d + (size_t)(n0 + n) * K + k0 + c;
  ((uint4*)dp)[0] = tv[0];
  ((uint4*)dp)[1] = tv[1];
}

// ---------------- router: logits, softmax, top-2; bf16 x; per-block prob partials ----------------
__global__ __launch_bounds__(256) void router_kernel(
    const float* __restrict__ x, const float* __restrict__ gw, const float* __restrict__ gb,
    __hip_bfloat16* __restrict__ xb, int* __restrict__ e12, float2* __restrict__ pfr,
    float* __restrict__ blkps)
{
  __shared__ float lps[4][8];
  const int l = threadIdx.x & 63;
  const int w = threadIdx.x >> 6;
  const int t = blockIdx.x * 4 + w;
  const float4* xr = (const float4*)(x + (size_t)t * D_MODEL);
  bh4* xbr = (bh4*)(xb + (size_t)t * D_MODEL);
  float a[8] = {0, 0, 0, 0, 0, 0, 0, 0};
#pragma unroll
  for (int c = 0; c < 4; ++c) {
    int idx = c * 64 + l;
    float4 v = xr[idx];
    bh4 hb;
    hb.x = __float2bfloat16(v.x); hb.y = __float2bfloat16(v.y);
    hb.z = __float2bfloat16(v.z); hb.w = __float2bfloat16(v.w);
    xbr[idx] = hb;
    const float* g = gw + (size_t)idx * 32;  // 4 rows x 8 experts
#pragma unroll
    for (int j = 0; j < 4; ++j) {
      float xv = (&v.x)[j];
#pragma unroll
      for (int e = 0; e < 8; ++e) a[e] = fmaf(xv, g[j * 8 + e], a[e]);
    }
  }
#pragma unroll
  for (int e = 0; e < 8; ++e) {
    float s = a[e];
#pragma unroll
    for (int off = 32; off > 0; off >>= 1) s += __shfl_xor(s, off, 64);
    a[e] = s + gb[e];
  }
  float m = a[0];
#pragma unroll
  for (int e = 1; e < 8; ++e) m = fmaxf(m, a[e]);
  float p[8], s = 0.f;
#pragma unroll
  for (int e = 0; e < 8; ++e) { p[e] = expf(a[e] - m); s += p[e]; }
  float inv = 1.0f / s;
#pragma unroll
  for (int e = 0; e < 8; ++e) p[e] *= inv;
  int e1 = 0; float p1 = p[0];
#pragma unroll
  for (int e = 1; e < 8; ++e) if (p[e] > p1) { p1 = p[e]; e1 = e; }
  int e2 = (e1 == 0) ? 1 : 0; float p2 = p[e2];
#pragma unroll
  for (int e = 0; e < 8; ++e) if (e != e1 && p[e] > p2) { p2 = p[e]; e2 = e; }

  if (l < 8) lps[w][l] = p[l];
  if (l == 0) {
    float rs = 1.0f / (p1 + p2);
    e12[t] = e1 | (e2 << 8);
    pfr[t] = make_float2(p1 * rs, p2 * rs);
  }
  __syncthreads();
  if (threadIdx.x < 8)
    blkps[(size_t)blockIdx.x * 8 + threadIdx.x] =
        lps[0][threadIdx.x] + lps[1][threadIdx.x] + lps[2][threadIdx.x] + lps[3][threadIdx.x];
}

// ---------------- count: ballot-based per-block expert counts (deterministic, atomic-free) --------
__global__ __launch_bounds__(256) void count_kernel(
    const int* __restrict__ e12, int* __restrict__ sblkcnt)
{
  __shared__ int wcnt[4][8];
  const int t = threadIdx.x, b = blockIdx.x, w = t >> 6, l = t & 63;
  int ee = e12[b * 256 + t];
  int e1 = ee & 0xff, e2 = ee >> 8;
#pragma unroll
  for (int k = 0; k < 8; ++k) {
    unsigned long long c1 = __ballot(e1 == k);
    unsigned long long c2 = __ballot(e2 == k);
    if (l == 0) wcnt[w][k] = __popcll(c1) + __popcll(c2);
  }
  __syncthreads();
  if (t < 8) sblkcnt[b * 8 + t] = wcnt[0][t] + wcnt[1][t] + wcnt[2][t] + wcnt[3][t];
}

// ---------------- finalize: sole writer of ctrl/bases; stats to out tail ----------------
__global__ __launch_bounds__(256) void finalize_kernel(
    int* __restrict__ ctrl, const float* __restrict__ blkps, const int* __restrict__ sblkcnt,
    int* __restrict__ bases, float* __restrict__ out_tail)
{
  __shared__ float part[256];
  __shared__ float ps[8];
  __shared__ int scnt[8];
  const int t = threadIdx.x;
  // reduce blkps[2048][8]
  const int e = t & 7, ch = t >> 3;
  float s = 0.f;
  for (int i = 0; i < 64; ++i) s += blkps[(size_t)(ch * 64 + i) * 8 + e];
  part[t] = s;
  __syncthreads();
  if (t < 8) {
    float a = 0.f;
    for (int c = 0; c < 32; ++c) a += part[c * 8 + t];
    ps[t] = a;
    int cn = 0;
    for (int b = 0; b < 32; ++b) cn += sblkcnt[b * 8 + t];
    scnt[t] = cn;
    ctrl[t] = cn;
    out_tail[t] = (float)cn * (1.0f / 16384.0f);
  }
  __syncthreads();
  if (t < 8) {
    int eo = 0;
    for (int i = 0; i < t; ++i) eo += scnt[i];
    ctrl[16 + t] = eo;
    int run = eo;
    for (int b = 0; b < 32; ++b) { bases[b * 8 + t] = run; run += sblkcnt[b * 8 + t]; }
    if (t == 0) {
      float mean = 0.f;
      for (int i = 0; i < 8; ++i) mean += ps[i];
      mean *= (1.0f / 8192.0f) * 0.125f;
      float v = 0.f;
      for (int i = 0; i < 8; ++i) { float d = ps[i] * (1.0f / 8192.0f) - mean; v += d * d; }
      out_tail[8] = v * (1.0f / 7.0f);  // ddof=1
    }
  }
}

// ---------------- place: ballot-ranked deterministic placement (atomic-free) ----------------
__global__ __launch_bounds__(256) void place_kernel(
    const int* __restrict__ e12, const float2* __restrict__ pfr, const int* __restrict__ bases,
    int* __restrict__ atok, float* __restrict__ ap)
{
  __shared__ int wcnt[4][8];
  const int t = threadIdx.x, b = blockIdx.x, w = t >> 6, l = t & 63;
  int tok = b * 256 + t;
  int ee = e12[tok];
  int e1 = ee & 0xff, e2 = ee >> 8;
  float2 p = pfr[tok];
  unsigned long long myA = 0, myA2 = 0, myB = 0;
#pragma unroll
  for (int k = 0; k < 8; ++k) {
    unsigned long long c1 = __ballot(e1 == k);
    unsigned long long c2 = __ballot(e2 == k);
    if (k == e1) myA = c1;
    if (k == e2) { myA2 = c1; myB = c2; }
    if (l == 0) wcnt[w][k] = __popcll(c1) + __popcll(c2);
  }
  __syncthreads();
  int base1 = bases[b * 8 + e1];
  int base2 = bases[b * 8 + e2];
  for (int w2 = 0; w2 < 4; ++w2) {
    if (w2 < w) { base1 += wcnt[w2][e1]; base2 += wcnt[w2][e2]; }
  }
  unsigned long long below = ((unsigned long long)1 << l) - 1;
  int pos1 = base1 + __popcll(myA & below);
  int pos2 = base2 + __popcll(myA2) + __popcll(myB & below);
  atok[pos1] = tok; ap[pos1] = p.x;
  atok[pos2] = tok; ap[pos2] = p.y;
}

// ---------------- grouped GEMM, 128x128 tile, BK=64, 16x16x32 bf16 MFMA ----------------
// G1: h[slot][4096] = relu( xb[tok[slot]][1024] @ w1t^T + b1 )   (w1t is [N][K]); y = mt
// G2: out[tok][1024] += ap[slot] * ( h[slot][4096] @ w2t^T + b2 ); y = (mt<<1)|ks, split-K=2
template <bool G1>
__global__ __launch_bounds__(256) void moe_gemm_kernel(
    const __hip_bfloat16* __restrict__ A, const __hip_bfloat16* __restrict__ Bw,
    const float* __restrict__ bias, __hip_bfloat16* __restrict__ Hout,
    float* __restrict__ Oout, const int* __restrict__ ctrl,
    const int* __restrict__ atok, const float* __restrict__ ap)
{
  constexpr int KD = G1 ? D_MODEL : D_FF;
  constexpr int ND = G1 ? D_FF : D_MODEL;
  constexpr int KRUN = G1 ? (KD / 64) : (KD / 128);  // G2: split-K=2
  const int e = blockIdx.z;
  const int cte = ctrl[e];
  int mt, ks;
  if constexpr (G1) { mt = blockIdx.y; ks = 0; }
  else              { mt = blockIdx.y >> 1; ks = blockIdx.y & 1; }
  if (mt * 128 >= cte) return;  // fixed worst-case grid, data-dependent live set
  const int n0 = blockIdx.x * 128;
  const int slot0 = ctrl[16 + e] + mt * 128;
  int cntLoc = cte - mt * 128; if (cntLoc > 128) cntLoc = 128;

  __shared__ ushort As[128 * 64];
  __shared__ ushort Bs[128 * 64];

  const int t = threadIdx.x, l = t & 63, w = t >> 6;
  const int kbase = ks * (KD / 2);  // element offset into K for this split

  // staging: chunk q = i*256+t covers (row = q>>3, lds-chunk = q&7); global chunk XOR-swizzled.
  const ushort* ag[4];
  const ushort* bg[4];
#pragma unroll
  for (int i = 0; i < 4; ++i) {
    int q = i * 256 + t;
    int row = q >> 3, cl = q & 7, cg = cl ^ (row & 7);
    int rr = row < cntLoc ? row : 0;  // clamp padded rows to a valid slot
    size_t arow;
    if constexpr (G1) arow = (size_t)atok[slot0 + rr] * D_MODEL;
    else              arow = (size_t)(slot0 + rr) * D_FF;
    ag[i] = (const ushort*)A + arow + kbase + cg * 8;
    bg[i] = (const ushort*)Bw + (size_t)e * ND * KD + (size_t)(n0 + row) * KD + kbase + cg * 8;
  }

  f32x4 acc[4][4] = {};
  const int wm = w & 1, wn = w >> 1;
  const int ml = l & 15, kg = l >> 4;

  for (int kt = 0; kt < KRUN; ++kt) {
#pragma unroll
    for (int i = 0; i < 4; ++i) {
      gll16(ag[i], &As[(i * 256 + w * 64) * 8]);
      ag[i] += 64;
    }
#pragma unroll
    for (int i = 0; i < 4; ++i) {
      gll16(bg[i], &Bs[(i * 256 + w * 64) * 8]);
      bg[i] += 64;
    }
    __syncthreads();
#pragma unroll
    for (int kss = 0; kss < 2; ++kss) {
      s16x8 af[4], bf[4];
#pragma unroll
      for (int mi = 0; mi < 4; ++mi) {
        int row = wm * 64 + mi * 16 + ml;
        int c = kss * 4 + kg;
        af[mi] = *(const s16x8*)&As[row * 64 + ((c ^ (row & 7)) * 8)];
      }
#pragma unroll
      for (int ni = 0; ni < 4; ++ni) {
        int row = wn * 64 + ni * 16 + ml;
        int c = kss * 4 + kg;
        bf[ni] = *(const s16x8*)&Bs[row * 64 + ((c ^ (row & 7)) * 8)];
      }
#pragma unroll
      for (int mi = 0; mi < 4; ++mi)
#pragma unroll
        for (int ni = 0; ni < 4; ++ni)
          acc[mi][ni] = __builtin_amdgcn_mfma_f32_16x16x32_bf16(af[mi], bf[ni], acc[mi][ni], 0, 0, 0);
    }
    __syncthreads();
  }

  // C/D layout: col = lane&15, row = (lane>>4)*4 + reg
  const int lr = kg * 4, lc = ml;
  if constexpr (G1) {
#pragma unroll
    for (int ni = 0; ni < 4; ++ni) {
      int col = n0 + wn * 64 + ni * 16 + lc;
      float bv = bias[(size_t)e * ND + col];
#pragma unroll
      for (int mi = 0; mi < 4; ++mi) {
#pragma unroll
        for (int r = 0; r < 4; ++r) {
          int rl = wm * 64 + mi * 16 + lr + r;
          if (rl < cntLoc) {
            float vv = fmaxf(acc[mi][ni][r] + bv, 0.0f);
            Hout[(size_t)(slot0 + rl) * D_FF + col] = __float2bfloat16(vv);
          }
        }
      }
    }
  } else {
    float bv[4];
#pragma unroll
    for (int ni = 0; ni < 4; ++ni)
      bv[ni] = (ks == 0) ? bias[(size_t)e * ND + n0 + wn * 64 + ni * 16 + lc] : 0.0f;
#pragma unroll
    for (int mi = 0; mi < 4; ++mi) {
#pragma unroll
      for (int r = 0; r < 4; ++r) {
        int rl = wm * 64 + mi * 16 + lr + r;
        if (rl < cntLoc) {
          int slot = slot0 + rl;
          float p = ap[slot];
          float* orow = Oout + (size_t)atok[slot] * D_MODEL + n0;
#pragma unroll
          for (int ni = 0; ni < 4; ++ni) {
            int colL = wn * 64 + ni * 16 + lc;
            unsafeAtomicAdd(orow + colL, p * (acc[mi][ni][r] + bv[ni]));
          }
        }
      }
    }
  }
}

extern "C" void kernel_launch(void* const* d_in, const int* in_sizes, int n_in,
                              void* d_out, int out_size, void* d_ws, size_t ws_size,
                              hipStream_t stream)
{
  const float* x  = (const float*)d_in[0];
  const float* gw = (const float*)d_in[1];
  const float* gb = (const float*)d_in[2];
  const float* w1 = (const float*)d_in[3];
  const float* b1 = (const float*)d_in[4];
  const float* w2 = (const float*)d_in[5];
  const float* b2 = (const float*)d_in[6];
  float* out = (float*)d_out;
  char* ws = (char*)d_ws;

  int*    ctrl    = (int*)ws;
  int*    bases   = (int*)(ws + 1024);
  int*    sblkcnt = (int*)(ws + 3072);
  int*    e12  = (int*)(ws + OFF_E12);
  float2* pfr  = (float2*)(ws + OFF_PFR);
  int*    atok = (int*)(ws + OFF_ATOK);
  float*  ap   = (float*)(ws + OFF_AP);
  __hip_bfloat16* xb   = (__hip_bfloat16*)(ws + OFF_XB);
  __hip_bfloat16* w1t  = (__hip_bfloat16*)(ws + OFF_W1T);
  __hip_bfloat16* w2t  = (__hip_bfloat16*)(ws + OFF_W2T);
  __hip_bfloat16* hbuf = (__hip_bfloat16*)(ws + OFF_H);
  float*  blkps = (float*)(ws + OFF_H);   // aliases hbuf start; consumed before GEMM1 writes hbuf

  hipMemsetAsync(d_out, 0, (size_t)out_size * sizeof(float), stream);

  cvt_transpose_kernel<<<dim3(D_FF / 64, D_MODEL / 64, NE), 256, 0, stream>>>(w1, w1t, D_MODEL, D_FF);
  cvt_transpose_kernel<<<dim3(D_MODEL / 64, D_FF / 64, NE), 256, 0, stream>>>(w2, w2t, D_FF, D_MODEL);
  router_kernel<<<NTOK / 4, 256, 0, stream>>>(x, gw, gb, xb, e12, pfr, blkps);
  count_kernel<<<NTOK / 256, 256, 0, stream>>>(e12, sblkcnt);
  finalize_kernel<<<1, 256, 0, stream>>>(ctrl, blkps, sblkcnt, bases, out + OUT_MAIN);
  place_kernel<<<NTOK / 256, 256, 0, stream>>>(e12, pfr, bases, atok, ap);
  moe_gemm_kernel<true ><<<dim3(D_FF / 128, 64, NE), 256, 0, stream>>>(xb, w1t, b1, hbuf, nullptr, ctrl, atok, ap);
  moe_gemm_kernel<false><<<dim3(D_MODEL / 128, 128, NE), 256, 0, stream>>>(hbuf, w2t, b2, nullptr, out, ctrl, atok, ap);
}